// Round 3
// baseline (1335.151 us; speedup 1.0000x reference)
//
#include <hip/hip_runtime.h>
#include <hip/hip_bf16.h>

#define VOCAB 512
#define EMB   128
#define HID   64
#define BATCH 256
#define TLEN  1024

__device__ __forceinline__ float fast_tanh(float x) {
    // tanh(x) = 1 - 2/(exp(2x)+1); exact at both saturated ends.
    float e = __expf(2.0f * x);
    return 1.0f - 2.0f / (e + 1.0f);
}

// ---------------------------------------------------------------------------
// Kernel 1: P0[v][i] = sum_e emb[v][e]*Wih0[i][e] + bih0[i] + bhh0[i]  (fp32)
// The entire layer-0 input path collapses to a 512x64 lookup table.
// ---------------------------------------------------------------------------
__global__ void __launch_bounds__(64) p0_kernel(
    const float* __restrict__ emb,
    const float* __restrict__ wih0,
    const float* __restrict__ bih0,
    const float* __restrict__ bhh0,
    float* __restrict__ P0)
{
    const int v = blockIdx.x;    // vocab row
    const int i = threadIdx.x;   // hidden index
    const float4* er = (const float4*)(emb  + v * EMB);
    const float4* wr = (const float4*)(wih0 + i * EMB);
    float a0 = 0.f, a1 = 0.f, a2 = 0.f, a3 = 0.f;
    #pragma unroll
    for (int k = 0; k < EMB / 4; ++k) {
        float4 e4 = er[k];
        float4 w4 = wr[k];
        a0 = fmaf(e4.x, w4.x, a0);
        a1 = fmaf(e4.y, w4.y, a1);
        a2 = fmaf(e4.z, w4.z, a2);
        a3 = fmaf(e4.w, w4.w, a3);
    }
    P0[v * HID + i] = (a0 + a1) + (a2 + a3) + bih0[i] + bhh0[i];
}

// ---------------------------------------------------------------------------
// Kernel 2: ONE WAVE per batch row — zero barriers.
// Cross-lane h-vector exchange uses same-wave LDS writes/reads (lockstep,
// DS-ordered; validated exact in R2's hs1 pattern). Global P0 prefetches are
// issued 2 steps (~1100 cyc) ahead and are never drained by a barrier.
// All three 64x64 weight rows live in VGPRs (192 regs) + 64-reg broadcast h0.
//   per step: h0 = tanh(a[x[s]] + Whh0 h0)          (64 FMA on hb0 regs)
//             h1 = tanh(b + Wih1 h0 + Whh1 h1)      (128 FMA)
// LDS roundtrip latencies hide under the independent matvecs.
// ---------------------------------------------------------------------------
__global__ void __launch_bounds__(64, 1) rnn_kernel(
    const int*   __restrict__ xs,
    const float* __restrict__ P0,
    const float* __restrict__ Whh0,
    const float* __restrict__ Wih1,
    const float* __restrict__ Whh1,
    const float* __restrict__ bih1,
    const float* __restrict__ bhh1,
    const float* __restrict__ W1,
    const float* __restrict__ b1,
    const float* __restrict__ W2,
    const float* __restrict__ b2,
    float*       __restrict__ out)
{
    __shared__ float h0buf[HID];
    __shared__ float h1buf[HID];

    const int b    = blockIdx.x;
    const int lane = threadIdx.x;   // 0..63, single wave

    // Resident weight rows (fp32): w0 = Whh0 row, w1 = Wih1 row, w2 = Whh1 row
    float w0[HID], w1[HID], w2[HID];
    {
        const float4* r0 = (const float4*)(Whh0 + lane * HID);
        const float4* r1 = (const float4*)(Wih1 + lane * HID);
        const float4* r2 = (const float4*)(Whh1 + lane * HID);
        #pragma unroll
        for (int k = 0; k < HID / 4; ++k) {
            float4 u0 = r0[k], u1 = r1[k], u2 = r2[k];
            w0[4*k+0]=u0.x; w0[4*k+1]=u0.y; w0[4*k+2]=u0.z; w0[4*k+3]=u0.w;
            w1[4*k+0]=u1.x; w1[4*k+1]=u1.y; w1[4*k+2]=u1.z; w1[4*k+3]=u1.w;
            w2[4*k+0]=u2.x; w2[4*k+1]=u2.y; w2[4*k+2]=u2.z; w2[4*k+3]=u2.w;
        }
    }
    const float b1s = bih1[lane] + bhh1[lane];

    h0buf[lane] = 0.f;
    h1buf[lane] = 0.f;

    // Broadcast copy of h0[s-1] (all lanes hold all 64 values)
    float hb0[HID];
    #pragma unroll
    for (int j = 0; j < HID; ++j) hb0[j] = 0.f;

    const int* xrow = xs + b * TLEN;
    // a_pre = P0 row for step s; a_nxt for s+1; xq = x index for step s+2
    float a_pre = P0[xrow[0] * HID + lane];
    float a_nxt = P0[xrow[1] * HID + lane];
    int   xq    = xrow[2];

    for (int s = 0; s < TLEN; ++s) {
        // ---- prefetch P0 row for step s+2 (xq already resident -> no stall)
        float a_n2 = P0[xq * HID + lane];
        int   xq_n = xrow[(s + 3 < TLEN) ? (s + 3) : (TLEN - 1)];

        // ---- layer 0: h0[s] = tanh(a_pre + Whh0 * h0[s-1])  (hb0 in regs)
        float ac0 = a_pre, ac1 = 0.f, ac2 = 0.f, ac3 = 0.f;
        #pragma unroll
        for (int k = 0; k < 16; ++k) {
            ac0 = fmaf(hb0[4*k+0], w0[4*k+0], ac0);
            ac1 = fmaf(hb0[4*k+1], w0[4*k+1], ac1);
            ac2 = fmaf(hb0[4*k+2], w0[4*k+2], ac2);
            ac3 = fmaf(hb0[4*k+3], w0[4*k+3], ac3);
        }
        float h0 = fast_tanh((ac0 + ac1) + (ac2 + ac3));
        h0buf[lane] = h0;                      // ds_write (lockstep)

        // ---- layer 1 part A: Whh1 * h1[s-1], streamed from LDS
        // (these reads depend only on last iteration's h1 write; their latency
        //  hides under this step's layer-0 FMA block and the h0 roundtrip
        //  hides under these FMAs)
        float bc0 = b1s, bc1 = 0.f, bc2 = 0.f, bc3 = 0.f;
        const float4* h14 = (const float4*)h1buf;
        #pragma unroll
        for (int k = 0; k < 16; ++k) {
            float4 hv = h14[k];
            bc0 = fmaf(hv.x, w2[4*k+0], bc0);
            bc1 = fmaf(hv.y, w2[4*k+1], bc1);
            bc2 = fmaf(hv.z, w2[4*k+2], bc2);
            bc3 = fmaf(hv.w, w2[4*k+3], bc3);
        }

        // ---- refresh broadcast h0 from LDS (write->read, same wave, ordered)
        {
            const float4* h04 = (const float4*)h0buf;
            #pragma unroll
            for (int k = 0; k < 16; ++k) {
                float4 hv = h04[k];
                hb0[4*k+0] = hv.x; hb0[4*k+1] = hv.y;
                hb0[4*k+2] = hv.z; hb0[4*k+3] = hv.w;
            }
        }

        // ---- layer 1 part B: + Wih1 * h0[s]
        #pragma unroll
        for (int k = 0; k < 16; ++k) {
            bc0 = fmaf(hb0[4*k+0], w1[4*k+0], bc0);
            bc1 = fmaf(hb0[4*k+1], w1[4*k+1], bc1);
            bc2 = fmaf(hb0[4*k+2], w1[4*k+2], bc2);
            bc3 = fmaf(hb0[4*k+3], w1[4*k+3], bc3);
        }
        float h1 = fast_tanh((bc0 + bc1) + (bc2 + bc3));
        h1buf[lane] = h1;                      // consumed next iteration

        a_pre = a_nxt;
        a_nxt = a_n2;
        xq    = xq_n;
    }

    // ---- MLP head: y = relu(h1 @ W1^T + b1) @ W2^T + b2
    float r = 0.f;
    if (lane < 32) {
        float acc = b1[lane];
        const float* w1r = W1 + lane * HID;
        #pragma unroll
        for (int j = 0; j < HID; ++j) acc = fmaf(w1r[j], h1buf[j], acc);
        r = fmaxf(acc, 0.f) * W2[lane];
    }
    #pragma unroll
    for (int off = 32; off > 0; off >>= 1) r += __shfl_down(r, off);
    if (lane == 0) out[b] = r + b2[0];
}

extern "C" void kernel_launch(void* const* d_in, const int* in_sizes, int n_in,
                              void* d_out, int out_size, void* d_ws, size_t ws_size,
                              hipStream_t stream)
{
    const int*   x    = (const int*)d_in[0];
    const float* emb  = (const float*)d_in[1];
    const float* Wih0 = (const float*)d_in[2];
    const float* Whh0 = (const float*)d_in[3];
    const float* bih0 = (const float*)d_in[4];
    const float* bhh0 = (const float*)d_in[5];
    const float* Wih1 = (const float*)d_in[6];
    const float* Whh1 = (const float*)d_in[7];
    const float* bih1 = (const float*)d_in[8];
    const float* bhh1 = (const float*)d_in[9];
    const float* W1   = (const float*)d_in[10];
    const float* b1   = (const float*)d_in[11];
    const float* W2   = (const float*)d_in[12];
    const float* b2   = (const float*)d_in[13];

    float* P0 = (float*)d_ws;   // 512*64*4 = 128 KiB scratch

    hipLaunchKernelGGL(p0_kernel, dim3(VOCAB), dim3(HID), 0, stream,
                       emb, Wih0, bih0, bhh0, P0);
    hipLaunchKernelGGL(rnn_kernel, dim3(BATCH), dim3(64), 0, stream,
                       x, P0, Whh0, Wih1, Whh1, bih1, bhh1,
                       W1, b1, W2, b2, (float*)d_out);
}

// Round 4
// 657.925 us; speedup vs baseline: 2.0293x; 2.0293x over previous
//
#include <hip/hip_runtime.h>
#include <hip/hip_bf16.h>

#define VOCAB 512
#define EMB   128
#define HID   64
#define BATCH 256
#define TLEN  1024

typedef float v2f __attribute__((ext_vector_type(2)));

__device__ __forceinline__ float fast_tanh(float x) {
    // tanh(x) = 1 - 2/(exp(2x)+1); exact at both saturated ends.
    float e = __expf(2.0f * x);
    return 1.0f - 2.0f / (e + 1.0f);
}

// ---------------------------------------------------------------------------
// Kernel 1: P0[v][i] = sum_e emb[v][e]*Wih0[i][e] + bih0[i] + bhh0[i]  (fp32)
// The entire layer-0 input path collapses to a 512x64 lookup table.
// ---------------------------------------------------------------------------
__global__ void __launch_bounds__(64) p0_kernel(
    const float* __restrict__ emb,
    const float* __restrict__ wih0,
    const float* __restrict__ bih0,
    const float* __restrict__ bhh0,
    float* __restrict__ P0)
{
    const int v = blockIdx.x;    // vocab row
    const int i = threadIdx.x;   // hidden index
    const float4* er = (const float4*)(emb  + v * EMB);
    const float4* wr = (const float4*)(wih0 + i * EMB);
    float a0 = 0.f, a1 = 0.f, a2 = 0.f, a3 = 0.f;
    #pragma unroll
    for (int k = 0; k < EMB / 4; ++k) {
        float4 e4 = er[k];
        float4 w4 = wr[k];
        a0 = fmaf(e4.x, w4.x, a0);
        a1 = fmaf(e4.y, w4.y, a1);
        a2 = fmaf(e4.z, w4.z, a2);
        a3 = fmaf(e4.w, w4.w, a3);
    }
    P0[v * HID + i] = (a0 + a1) + (a2 + a3) + bih0[i] + bhh0[i];
}

// ---------------------------------------------------------------------------
// Kernel 2: ONE WAVE per batch row — zero barriers, zero syncthreads.
// Register budget is the whole game (R3 post-mortem: >256 live floats made
// the allocator rematerialize weights from memory each step -> 3x slower).
// Live set here: 192 weight floats (as 96 packed v2f) + ~30 temps.
//   per step: h0 = tanh(P0[x[s]] + Whh0 h0)       (32 pk-FMA)
//             h1 = tanh(b + Wih1 h0 + Whh1 h1)    (64 pk-FMA)
// h broadcast via same-wave LDS write->read (DS-ordered, validated R2/R3).
// P0 gather prefetched 2 steps ahead; never drained (no barriers exist).
// x row staged in LDS up front -> the gather is the loop's only global op.
// ---------------------------------------------------------------------------
__global__ void __launch_bounds__(64, 1) rnn_kernel(
    const int*   __restrict__ xs,
    const float* __restrict__ P0,
    const float* __restrict__ Whh0,
    const float* __restrict__ Wih1,
    const float* __restrict__ Whh1,
    const float* __restrict__ bih1,
    const float* __restrict__ bhh1,
    const float* __restrict__ W1,
    const float* __restrict__ b1,
    const float* __restrict__ W2,
    const float* __restrict__ b2,
    float*       __restrict__ out)
{
    __shared__ float h0buf[HID];
    __shared__ float h1buf[HID];
    __shared__ int   xlds[TLEN + 2];

    const int b    = blockIdx.x;
    const int lane = threadIdx.x;   // 0..63, single wave

    // ---- stage x row into LDS (same-wave DS ordering; no barrier needed)
    const int* xrow = xs + b * TLEN;
    #pragma unroll
    for (int i = 0; i < TLEN / 64; ++i)
        xlds[lane + 64 * i] = xrow[lane + 64 * i];
    if (lane < 2) xlds[TLEN + lane] = xrow[TLEN - 1];

    // ---- resident weight rows as packed float2 pairs (96 v2f = 192 VGPRs)
    v2f w0[32], w1[32], w2[32];
    {
        const float4* r0 = (const float4*)(Whh0 + lane * HID);
        const float4* r1 = (const float4*)(Wih1 + lane * HID);
        const float4* r2 = (const float4*)(Whh1 + lane * HID);
        #pragma unroll
        for (int k = 0; k < HID / 4; ++k) {
            float4 u0 = r0[k], u1 = r1[k], u2 = r2[k];
            w0[2*k] = v2f{u0.x, u0.y}; w0[2*k+1] = v2f{u0.z, u0.w};
            w1[2*k] = v2f{u1.x, u1.y}; w1[2*k+1] = v2f{u1.z, u1.w};
            w2[2*k] = v2f{u2.x, u2.y}; w2[2*k+1] = v2f{u2.z, u2.w};
        }
    }
    const float b1s = bih1[lane] + bhh1[lane];

    h0buf[lane] = 0.f;
    h1buf[lane] = 0.f;

    // ---- prime P0 prefetch pipeline (rows for s=0 and s=1)
    float a_pre = P0[xrow[0] * HID + lane];
    float a_nxt = P0[xrow[1] * HID + lane];

    const float4* h04 = (const float4*)h0buf;
    const float4* h14 = (const float4*)h1buf;

    #pragma unroll 1
    for (int s = 0; s < TLEN; ++s) {
        // ---- issue P0 prefetch for step s+2 (lands in ~200-900 cyc; used
        //      ~1200 cyc from now; no barrier ever drains it)
        int   xn   = xlds[s + 2];
        float a_n2 = P0[xn * HID + lane];

        // ---- layer 0: h0[s] = tanh(a_pre + Whh0 * h0[s-1])
        v2f ac0 = v2f{a_pre, 0.f}, ac1 = v2f{0.f, 0.f};
        #pragma unroll
        for (int k = 0; k < 16; ++k) {
            float4 hv = h04[k];
            ac0 = __builtin_elementwise_fma(v2f{hv.x, hv.y}, w0[2*k],   ac0);
            ac1 = __builtin_elementwise_fma(v2f{hv.z, hv.w}, w0[2*k+1], ac1);
        }
        float h0 = fast_tanh((ac0.x + ac1.x) + (ac0.y + ac1.y));
        h0buf[lane] = h0;                     // ds_write (lockstep)

        // ---- layer 1 part A: b + Whh1 * h1[s-1]  (independent of h0 write;
        //      its ~130 cyc of issue covers the h0 LDS roundtrip)
        v2f bc0 = v2f{b1s, 0.f}, bc1 = v2f{0.f, 0.f};
        #pragma unroll
        for (int k = 0; k < 16; ++k) {
            float4 hv = h14[k];
            bc0 = __builtin_elementwise_fma(v2f{hv.x, hv.y}, w2[2*k],   bc0);
            bc1 = __builtin_elementwise_fma(v2f{hv.z, hv.w}, w2[2*k+1], bc1);
        }

        // ---- layer 1 part B: + Wih1 * h0[s]  (reads the fresh h0 broadcast)
        #pragma unroll
        for (int k = 0; k < 16; ++k) {
            float4 hv = h04[k];
            bc0 = __builtin_elementwise_fma(v2f{hv.x, hv.y}, w1[2*k],   bc0);
            bc1 = __builtin_elementwise_fma(v2f{hv.z, hv.w}, w1[2*k+1], bc1);
        }
        float h1 = fast_tanh((bc0.x + bc1.x) + (bc0.y + bc1.y));
        h1buf[lane] = h1;                     // consumed next iteration

        a_pre = a_nxt;
        a_nxt = a_n2;
    }

    // ---- MLP head: y = relu(h1 @ W1^T + b1) @ W2^T + b2
    float r = 0.f;
    if (lane < 32) {
        float acc = b1[lane];
        const float* w1r = W1 + lane * HID;
        #pragma unroll
        for (int j = 0; j < HID; ++j) acc = fmaf(w1r[j], h1buf[j], acc);
        r = fmaxf(acc, 0.f) * W2[lane];
    }
    #pragma unroll
    for (int off = 32; off > 0; off >>= 1) r += __shfl_down(r, off);
    if (lane == 0) out[b] = r + b2[0];
}

extern "C" void kernel_launch(void* const* d_in, const int* in_sizes, int n_in,
                              void* d_out, int out_size, void* d_ws, size_t ws_size,
                              hipStream_t stream)
{
    const int*   x    = (const int*)d_in[0];
    const float* emb  = (const float*)d_in[1];
    const float* Wih0 = (const float*)d_in[2];
    const float* Whh0 = (const float*)d_in[3];
    const float* bih0 = (const float*)d_in[4];
    const float* bhh0 = (const float*)d_in[5];
    const float* Wih1 = (const float*)d_in[6];
    const float* Whh1 = (const float*)d_in[7];
    const float* bih1 = (const float*)d_in[8];
    const float* bhh1 = (const float*)d_in[9];
    const float* W1   = (const float*)d_in[10];
    const float* b1   = (const float*)d_in[11];
    const float* W2   = (const float*)d_in[12];
    const float* b2   = (const float*)d_in[13];

    float* P0 = (float*)d_ws;   // 512*64*4 = 128 KiB scratch

    hipLaunchKernelGGL(p0_kernel, dim3(VOCAB), dim3(HID), 0, stream,
                       emb, Wih0, bih0, bhh0, P0);
    hipLaunchKernelGGL(rnn_kernel, dim3(BATCH), dim3(64), 0, stream,
                       x, P0, Whh0, Wih1, Whh1, bih1, bhh1,
                       W1, b1, W2, b2, (float*)d_out);
}

// Round 5
// 389.391 us; speedup vs baseline: 3.4288x; 1.6896x over previous
//
#include <hip/hip_runtime.h>
#include <hip/hip_bf16.h>

#define VOCAB 512
#define EMB   128
#define HID   64
#define BATCH 256
#define TLEN  1024
#define CH    16              // steps per chunk
#define NCH   (TLEN / CH)     // 64 chunks
#define RS    128             // ring depth in steps (8 chunks)
#define RCH   (RS / CH)       // 8 chunks per ring

typedef float v2f __attribute__((ext_vector_type(2)));

__device__ __forceinline__ float fast_tanh(float x) {
    // tanh(x) = 1 - 2/(exp(2x)+1); exact at both saturated ends.
    float e = __expf(2.0f * x);
    return 1.0f - 2.0f / (e + 1.0f);
}

// LDS-only fence: drains the DS queue WITHOUT touching vmcnt, so global
// prefetches stay in flight across flag publishes.
__device__ __forceinline__ void lds_fence() {
    asm volatile("s_waitcnt lgkmcnt(0)" ::: "memory");
}
__device__ __forceinline__ void compiler_fence() {
    asm volatile("" ::: "memory");
}

// ---------------------------------------------------------------------------
// Kernel 1: P0[v][i] = sum_e emb[v][e]*Wih0[i][e] + bih0[i] + bhh0[i]  (fp32)
// The entire layer-0 input path collapses to a 512x64 lookup table.
// ---------------------------------------------------------------------------
__global__ void __launch_bounds__(64) p0_kernel(
    const float* __restrict__ emb,
    const float* __restrict__ wih0,
    const float* __restrict__ bih0,
    const float* __restrict__ bhh0,
    float* __restrict__ P0)
{
    const int v = blockIdx.x;    // vocab row
    const int i = threadIdx.x;   // hidden index
    const float4* er = (const float4*)(emb  + v * EMB);
    const float4* wr = (const float4*)(wih0 + i * EMB);
    float a0 = 0.f, a1 = 0.f, a2 = 0.f, a3 = 0.f;
    #pragma unroll
    for (int k = 0; k < EMB / 4; ++k) {
        float4 e4 = er[k];
        float4 w4 = wr[k];
        a0 = fmaf(e4.x, w4.x, a0);
        a1 = fmaf(e4.y, w4.y, a1);
        a2 = fmaf(e4.z, w4.z, a2);
        a3 = fmaf(e4.w, w4.w, a3);
    }
    P0[v * HID + i] = (a0 + a1) + (a2 + a3) + bih0[i] + bhh0[i];
}

// ---------------------------------------------------------------------------
// Kernel 2: DECOUPLED 3-wave pipeline, one block per batch row.
//   wave0: h0[t] = tanh(P0[x[t]] + Whh0 h0[t-1])      (recurrent)
//   wave1: p1[t] = b1 + Wih1 h0[t]                     (no recurrence)
//   wave2: h1[t] = tanh(p1[t] + Whh1 h1[t-1])          (recurrent)
// Each wave holds exactly 64 weight floats/lane (proven register-resident in
// R2 at 88 VGPRs; 192 floats provably rematerializes — R3/R4). Waves run
// chunks of CH=16 steps decoupled through 128-step LDS rings; sync is one
// LDS flag per chunk (lgkmcnt-only fence), NOT __syncthreads — so wave0's
// global P0 prefetch queue is never drained (R2's ~800 cyc/step barrier tax
// eliminated). No deadlock: dependency edges w1<-w0, w2<-w1 plus
// back-pressure w0<-w1(k-8), w1<-w2(k-8) form no cycle at any reachable k.
// ---------------------------------------------------------------------------
__global__ void __launch_bounds__(192, 1) rnn_kernel(
    const int*   __restrict__ xs,
    const float* __restrict__ P0,
    const float* __restrict__ Whh0,
    const float* __restrict__ Wih1,
    const float* __restrict__ Whh1,
    const float* __restrict__ bih1,
    const float* __restrict__ bhh1,
    const float* __restrict__ W1,
    const float* __restrict__ b1,
    const float* __restrict__ W2,
    const float* __restrict__ b2,
    float*       __restrict__ out)
{
    __shared__ float h0ring[RS][HID];   // 32 KiB
    __shared__ float p1ring[RS][HID];   // 32 KiB
    __shared__ float h1buf[2][HID];
    __shared__ int   xlds[TLEN];        // 4 KiB
    __shared__ int   flags[3];          // completed-chunk counters f0,f1,f2

    const int b    = blockIdx.x;
    const int tid  = threadIdx.x;
    const int wv   = tid >> 6;
    const int lane = tid & 63;

    const int* xrow = xs + b * TLEN;

    if (wv == 0) {
        #pragma unroll
        for (int i = 0; i < TLEN / 64; ++i)
            xlds[lane + 64 * i] = xrow[lane + 64 * i];
        h0ring[RS - 1][lane] = 0.f;      // h0[-1] = 0
    } else if (wv == 2) {
        h1buf[0][lane] = 0.f;            // h1[-1] = 0
        h1buf[1][lane] = 0.f;
    }
    if (tid < 3) flags[tid] = 0;
    __syncthreads();                     // the ONLY barrier in the kernel

    // Per-wave weight row -> 32 packed v2f (64 VGPRs), loop-invariant.
    const float* wmat = (wv == 0) ? Whh0 : (wv == 1) ? Wih1 : Whh1;
    v2f w[32];
    {
        const float4* wr = (const float4*)(wmat + lane * HID);
        #pragma unroll
        for (int k = 0; k < 16; ++k) {
            float4 u = wr[k];
            w[2 * k]     = v2f{u.x, u.y};
            w[2 * k + 1] = v2f{u.z, u.w};
        }
    }

    volatile int* vf = (volatile int*)flags;

    if (wv == 0) {
        // ---- layer-0 recurrence ----
        float a_pre = P0[xrow[0] * HID + lane];
        float a_nxt = P0[xrow[1] * HID + lane];
        #pragma unroll 1
        for (int k = 0; k < NCH; ++k) {
            if (k >= RCH) {                       // slot reuse guard
                while (vf[1] < k - (RCH - 1)) {}
                compiler_fence();
            }
            const int base = (k & (RCH - 1)) * CH;
            const int t0   = k * CH;
            #pragma unroll
            for (int i = 0; i < CH; ++i) {
                const int t   = t0 + i;
                const int pix = (t + 2 < TLEN) ? (t + 2) : (TLEN - 1);
                float a_n2 = P0[xlds[pix] * HID + lane];   // prefetch s+2
                const float4* hp = (const float4*)h0ring[(base + i - 1) & (RS - 1)];
                v2f ac0 = v2f{a_pre, 0.f}, ac1 = v2f{0.f, 0.f};
                #pragma unroll
                for (int q = 0; q < 16; ++q) {
                    float4 hv = hp[q];
                    ac0 = __builtin_elementwise_fma(v2f{hv.x, hv.y}, w[2*q],   ac0);
                    ac1 = __builtin_elementwise_fma(v2f{hv.z, hv.w}, w[2*q+1], ac1);
                }
                h0ring[base + i][lane] =
                    fast_tanh((ac0.x + ac1.x) + (ac0.y + ac1.y));
                a_pre = a_nxt;
                a_nxt = a_n2;
            }
            lds_fence();                          // DS queue only, NOT vmcnt
            if (lane == 0) vf[0] = k + 1;
        }
    } else if (wv == 1) {
        // ---- layer-1 input projection (no recurrence: pure throughput) ----
        const float b1s = bih1[lane] + bhh1[lane];
        #pragma unroll 1
        for (int k = 0; k < NCH; ++k) {
            while (vf[0] < k + 1) {}
            if (k >= RCH) { while (vf[2] < k - (RCH - 1)) {} }
            compiler_fence();
            const int base = (k & (RCH - 1)) * CH;
            #pragma unroll
            for (int i = 0; i < CH; ++i) {
                const float4* hp = (const float4*)h0ring[base + i];
                v2f ac0 = v2f{b1s, 0.f}, ac1 = v2f{0.f, 0.f};
                #pragma unroll
                for (int q = 0; q < 16; ++q) {
                    float4 hv = hp[q];
                    ac0 = __builtin_elementwise_fma(v2f{hv.x, hv.y}, w[2*q],   ac0);
                    ac1 = __builtin_elementwise_fma(v2f{hv.z, hv.w}, w[2*q+1], ac1);
                }
                p1ring[base + i][lane] = (ac0.x + ac1.x) + (ac0.y + ac1.y);
            }
            lds_fence();
            if (lane == 0) vf[1] = k + 1;
        }
    } else {
        // ---- layer-1 recurrence ----
        #pragma unroll 1
        for (int k = 0; k < NCH; ++k) {
            while (vf[1] < k + 1) {}
            compiler_fence();
            const int base = (k & (RCH - 1)) * CH;
            float p[CH];                           // prefetch whole chunk
            #pragma unroll
            for (int i = 0; i < CH; ++i) p[i] = p1ring[base + i][lane];
            #pragma unroll
            for (int i = 0; i < CH; ++i) {
                const int t = k * CH + i;
                const float4* hp = (const float4*)h1buf[(t + 1) & 1];
                v2f ac0 = v2f{p[i], 0.f}, ac1 = v2f{0.f, 0.f};
                #pragma unroll
                for (int q = 0; q < 16; ++q) {
                    float4 hv = hp[q];
                    ac0 = __builtin_elementwise_fma(v2f{hv.x, hv.y}, w[2*q],   ac0);
                    ac1 = __builtin_elementwise_fma(v2f{hv.z, hv.w}, w[2*q+1], ac1);
                }
                h1buf[t & 1][lane] =
                    fast_tanh((ac0.x + ac1.x) + (ac0.y + ac1.y));
            }
            lds_fence();                           // p1 reads consumed
            if (lane == 0) vf[2] = k + 1;
        }
        // ---- MLP head: y = relu(h1 @ W1^T + b1) @ W2^T + b2 ----
        float r = 0.f;
        if (lane < 32) {
            float acc = b1[lane];
            const float* w1r = W1 + lane * HID;
            const float* hN  = h1buf[(TLEN - 1) & 1];
            #pragma unroll
            for (int j = 0; j < HID; ++j) acc = fmaf(w1r[j], hN[j], acc);
            r = fmaxf(acc, 0.f) * W2[lane];
        }
        #pragma unroll
        for (int off = 32; off > 0; off >>= 1) r += __shfl_down(r, off);
        if (lane == 0) out[b] = r + b2[0];
    }
}

extern "C" void kernel_launch(void* const* d_in, const int* in_sizes, int n_in,
                              void* d_out, int out_size, void* d_ws, size_t ws_size,
                              hipStream_t stream)
{
    const int*   x    = (const int*)d_in[0];
    const float* emb  = (const float*)d_in[1];
    const float* Wih0 = (const float*)d_in[2];
    const float* Whh0 = (const float*)d_in[3];
    const float* bih0 = (const float*)d_in[4];
    const float* bhh0 = (const float*)d_in[5];
    const float* Wih1 = (const float*)d_in[6];
    const float* Whh1 = (const float*)d_in[7];
    const float* bih1 = (const float*)d_in[8];
    const float* bhh1 = (const float*)d_in[9];
    const float* W1   = (const float*)d_in[10];
    const float* b1   = (const float*)d_in[11];
    const float* W2   = (const float*)d_in[12];
    const float* b2   = (const float*)d_in[13];

    float* P0 = (float*)d_ws;   // 512*64*4 = 128 KiB scratch

    hipLaunchKernelGGL(p0_kernel, dim3(VOCAB), dim3(HID), 0, stream,
                       emb, Wih0, bih0, bhh0, P0);
    hipLaunchKernelGGL(rnn_kernel, dim3(BATCH), dim3(192), 0, stream,
                       x, P0, Whh0, Wih1, Whh1, bih1, bhh1,
                       W1, b1, W2, b2, (float*)d_out);
}